// Round 26
// baseline (153.302 us; speedup 1.0000x reference)
//
#include <hip/hip_runtime.h>

// Round 26: exact r25 pipeline; ONLY change = gagg ILP-16 (unmasked 16-wide
// main loop + one masked 16-wide tail) — halves dependent latency rounds/node.

#define HD 128
#define TD 64
#define BSH 7                 // 128 nodes per bucket
#define NBLK 256              // passA blocks (= regions per bucket)
constexpr float SLOPE = 11.0f / 48.0f;

typedef unsigned short u16;
typedef unsigned int u32;
typedef short bf16x8 __attribute__((ext_vector_type(8)));
typedef float f32x4 __attribute__((ext_vector_type(4)));

__device__ __forceinline__ float bf2f(u16 b) {
    return __uint_as_float(((u32)b) << 16);
}
__device__ __forceinline__ u16 f2bf(float f) {
    u32 u = __float_as_uint(f);
    u += 0x7FFFu + ((u >> 16) & 1u);  // RNE
    return (u16)(u >> 16);
}

// ---- fp32 -> bf16 convert -------------------------------------------------
__global__ __launch_bounds__(256)
void conv_kernel(const float4* __restrict__ in, ushort4* __restrict__ out, int n4)
{
    int i = blockIdx.x * 256 + threadIdx.x;
    if (i >= n4) return;
    float4 v = in[i];
    ushort4 o;
    o.x = f2bf(v.x); o.y = f2bf(v.y); o.z = f2bf(v.z); o.w = f2bf(v.w);
    out[i] = o;
}

// ---- build BT[col][k] bf16, k<128 from Wn, k>=128 from Lw ------------------
__global__ __launch_bounds__(256)
void bt_kernel(const float* __restrict__ Wn, const float* __restrict__ Lw,
               u16* __restrict__ BT)
{
    int idx = blockIdx.x * 256 + threadIdx.x;   // 128*256 = 32768
    int c = idx >> 8, k = idx & 255;
    float v = (k < HD) ? Wn[k * HD + c] : Lw[(k - HD) * HD + c];
    BT[(size_t)c * 256 + k] = f2bf(v);
}

// ---- cntA: per-block bucket histogram -> cnt[bucket*NBLK + blk] ------------
__global__ __launch_bounds__(256)
void cntA(const int* __restrict__ dst, int E, int* __restrict__ cnt, int NBKT)
{
    __shared__ int hist[512];
    const int b = blockIdx.x, t = threadIdx.x;
    for (int i = t; i < NBKT; i += 256) hist[i] = 0;
    __syncthreads();
    const int chunk = (E + NBLK - 1) / NBLK;
    const int e0 = b * chunk;
    const int e1 = (e0 + chunk < E) ? e0 + chunk : E;
    for (int e = e0 + t; e < e1; e += 256)
        atomicAdd(&hist[dst[e] >> BSH], 1);
    __syncthreads();
    for (int i = t; i < NBKT; i += 256)
        cnt[(size_t)i * NBLK + b] = hist[i];
}

// ---- hierarchical exclusive scan over M = NBKT*NBLK values -----------------
__global__ __launch_bounds__(256)
void scan1_kernel(const int* __restrict__ v, int* __restrict__ bsum, int M)
{
    __shared__ int red[256];
    const int b = blockIdx.x, t = threadIdx.x;
    int s = 0;
    #pragma unroll
    for (int j = 0; j < 4; j++) {
        int i = b * 1024 + j * 256 + t;
        if (i < M) s += v[i];
    }
    red[t] = s;
    __syncthreads();
    for (int off = 128; off; off >>= 1) {
        if (t < off) red[t] += red[t + off];
        __syncthreads();
    }
    if (t == 0) bsum[b] = red[0];
}

__global__ __launch_bounds__(64)
void scan2_kernel(int* __restrict__ bsum, int NB, int* __restrict__ totalOut)
{
    if (threadIdx.x == 0 && blockIdx.x == 0) {
        int acc = 0;
        for (int b = 0; b < NB; b++) { int x = bsum[b]; bsum[b] = acc; acc += x; }
        *totalOut = acc;   // == E
    }
}

__global__ __launch_bounds__(1024)
void scan3_kernel(const int* __restrict__ v, const int* __restrict__ bsum,
                  int* __restrict__ start, int M)
{
    __shared__ int buf[1024];
    const int b = blockIdx.x, t = threadIdx.x;
    const int i = b * 1024 + t;
    const int x = (i < M) ? v[i] : 0;
    buf[t] = x;
    __syncthreads();
    for (int off = 1; off < 1024; off <<= 1) {
        int y = (t >= off) ? buf[t - off] : 0;
        __syncthreads();
        buf[t] += y;
        __syncthreads();
    }
    if (i < M) start[i] = bsum[b] + buf[t] - x;   // exclusive
}

// ---- passA2: append via per-block LDS cursors (no global atomics) ----------
// entry = (dloc<<25) | (ety<<16) | src
__global__ __launch_bounds__(256)
void passA2(const int* __restrict__ src, const int* __restrict__ dst,
            const int* __restrict__ ety, const int* __restrict__ start,
            u32* __restrict__ elistA, int E, int NBKT)
{
    __shared__ int cur[512];
    const int b = blockIdx.x, t = threadIdx.x;
    for (int i = t; i < NBKT; i += 256) cur[i] = start[(size_t)i * NBLK + b];
    __syncthreads();
    const int chunk = (E + NBLK - 1) / NBLK;
    const int e0 = b * chunk;
    const int e1 = (e0 + chunk < E) ? e0 + chunk : E;
    for (int e = e0 + t; e < e1; e += 256) {
        int d = dst[e];
        u32 entry = ((u32)(d & 127) << 25) | ((u32)ety[e] << 16) | (u32)src[e];
        int pos = atomicAdd(&cur[d >> BSH], 1);
        elistA[pos] = entry;
    }
}

// ---- passB: per-bucket sort into per-node CSR + rowstart -------------------
__global__ __launch_bounds__(256)
void passB(const u32* __restrict__ elistA, const int* __restrict__ start,
           u32* __restrict__ elist, int* __restrict__ rowstart, int Nn, int E,
           int NBKT)
{
    __shared__ int cnt[128];
    __shared__ int ofs[128];
    const int b = blockIdx.x, t = threadIdx.x;
    const int beg = start[(size_t)b * NBLK];
    const int end = (b + 1 < NBKT) ? start[(size_t)(b + 1) * NBLK] : E;
    if (t < 128) cnt[t] = 0;
    __syncthreads();
    for (int i = beg + t; i < end; i += 256)
        atomicAdd(&cnt[elistA[i] >> 25], 1);
    __syncthreads();
    if (t == 0) {
        int acc = 0;
        for (int j = 0; j < 128; j++) { ofs[j] = acc; acc += cnt[j]; }
    }
    __syncthreads();
    const int n0 = b << BSH;
    if (t < 128 && n0 + t < Nn) rowstart[n0 + t] = beg + ofs[t];
    if (b == 0 && t == 0) rowstart[Nn] = E;
    __syncthreads();
    for (int i = beg + t; i < end; i += 256) {
        u32 v = elistA[i];
        int p = atomicAdd(&ofs[v >> 25], 1);
        elist[beg + p] = v & 0x01ffffffu;   // (ety<<16)|src
    }
}

// ---- gather-aggregate (bf16 h + bf16 rel), pre-scaled by 1/max(deg,1) ------
// block = one dst node, 64 threads; thread c owns cols 2c, 2c+1 (u32 = 2 bf16)
// ILP-16: unmasked 16-wide main loop + one masked 16-wide tail.
__global__ __launch_bounds__(64)
void gagg_kernel(const u32* __restrict__ hbf2, const u32* __restrict__ relbf2,
                 const u32* __restrict__ elist, const int* __restrict__ rowstart,
                 u32* __restrict__ Sn2, int Nn)
{
    int n = blockIdx.x;
    if (n >= Nn) return;
    int c = threadIdx.x;
    int beg = rowstart[n], end = rowstart[n + 1];
    float ae[8] = {}, ao[8] = {};
    int i = beg;
    for (; i + 16 <= end; i += 16) {
        #pragma unroll
        for (int j = 0; j < 16; j++) {
            u32 v = elist[i + j];
            u32 hv = hbf2[(size_t)(v & 0xffffu) * 64 + c];
            u32 rv = relbf2[(size_t)(v >> 16) * 64 + c];
            ae[j & 7] += bf2f((u16)(hv & 0xffffu)) - bf2f((u16)(rv & 0xffffu));
            ao[j & 7] += bf2f((u16)(hv >> 16)) - bf2f((u16)(rv >> 16));
        }
    }
    if (i < end) {
        // masked ILP-16 tail (beg < end here, so elist[beg] is always valid)
        #pragma unroll
        for (int j = 0; j < 16; j++) {
            int idx = i + j;
            bool ok = idx < end;
            u32 v = elist[ok ? idx : beg];
            u32 hv = hbf2[(size_t)(v & 0xffffu) * 64 + c];
            u32 rv = relbf2[(size_t)(v >> 16) * 64 + c];
            float de = bf2f((u16)(hv & 0xffffu)) - bf2f((u16)(rv & 0xffffu));
            float doo = bf2f((u16)(hv >> 16)) - bf2f((u16)(rv >> 16));
            ae[j & 7] += ok ? de : 0.0f;
            ao[j & 7] += ok ? doo : 0.0f;
        }
    }
    float se = ((ae[0] + ae[1]) + (ae[2] + ae[3])) + ((ae[4] + ae[5]) + (ae[6] + ae[7]));
    float so = ((ao[0] + ao[1]) + (ao[2] + ao[3])) + ((ao[4] + ao[5]) + (ao[6] + ao[7]));
    int d = end - beg;
    float nrm = 1.0f / (float)((d > 0) ? d : 1);
    se *= nrm; so *= nrm;
    Sn2[(size_t)n * 64 + c] = (u32)f2bf(se) | ((u32)f2bf(so) << 16);
}

// ---- MFMA GEMM: out = rrelu([Sn | Hn](bf16, K=256) @ BT^T), BT in LDS ------
__global__ __launch_bounds__(256)
void mfma_kernel(const u16* __restrict__ Sn, const u16* __restrict__ Hn,
                 const u16* __restrict__ BT, const int* __restrict__ rowstart,
                 const float* __restrict__ Ew, u16* __restrict__ Out, int Nn)
{
    __shared__ u16 BTs[128 * 256];   // 64 KB, swizzled

    const int tid = threadIdx.x;
    #pragma unroll
    for (int j = 0; j < 16; j++) {
        int chunk = tid + j * 256;
        int byte = chunk << 4;
        int row = byte >> 9;
        int sw = byte ^ ((row & 7) << 4);
        *(ulonglong2*)((char*)BTs + sw) = *(const ulonglong2*)((const char*)BT + byte);
    }
    __syncthreads();

    const int lane = tid & 63;
    const int wave = tid >> 6;
    const int row0 = blockIdx.x * 128 + wave * 32;
    const int lr = lane & 15;
    const int lk = (lane >> 4) * 8;

    f32x4 acc[2][8];
    #pragma unroll
    for (int m = 0; m < 2; m++)
        #pragma unroll
        for (int n = 0; n < 8; n++)
            acc[m][n] = (f32x4){0.f, 0.f, 0.f, 0.f};

    int r0 = row0 + lr;      if (r0 >= Nn) r0 = Nn - 1;
    int r1 = row0 + 16 + lr; if (r1 >= Nn) r1 = Nn - 1;
    const size_t rb0 = (size_t)r0 * HD, rb1 = (size_t)r1 * HD;

    #pragma unroll
    for (int ks = 0; ks < 8; ks++) {
        const u16* A = (ks < 4) ? Sn : Hn;
        const int kc = (ks & 3) * 32 + lk;
        bf16x8 a0 = *(const bf16x8*)&A[rb0 + kc];
        bf16x8 a1 = *(const bf16x8*)&A[rb1 + kc];
        #pragma unroll
        for (int nf = 0; nf < 8; nf++) {
            const int brow = nf * 16 + lr;
            int boff = (brow << 9) + ((ks * 32 + lk) << 1);
            boff ^= (brow & 7) << 4;
            bf16x8 b = *(const bf16x8*)((const char*)BTs + boff);
            acc[0][nf] = __builtin_amdgcn_mfma_f32_16x16x32_bf16(a0, b, acc[0][nf], 0, 0, 0);
            acc[1][nf] = __builtin_amdgcn_mfma_f32_16x16x32_bf16(a1, b, acc[1][nf], 0, 0, 0);
        }
    }

    #pragma unroll
    for (int mf = 0; mf < 2; mf++) {
        #pragma unroll
        for (int r = 0; r < 4; r++) {
            const int row = row0 + mf * 16 + (lane >> 4) * 4 + r;
            if (row >= Nn) continue;
            const int d = rowstart[row + 1] - rowstart[row];
            #pragma unroll
            for (int nf = 0; nf < 8; nf++) {
                const int col = nf * 16 + lr;
                float o = acc[mf][nf][r];
                if (d == 0) {
                    // isolated node (rare): Sn row is 0; loop term must use Ew
                    o = 0.f;
                    for (int k = 0; k < HD; k++)
                        o = fmaf(bf2f(Hn[(size_t)row * HD + k]), Ew[(size_t)k * HD + col], o);
                }
                o = (o >= 0.f) ? o : o * SLOPE;
                Out[(size_t)row * HD + col] = f2bf(o);
            }
        }
    }
}

// ---- gather + time embedding -> FP32 output [R, 192]; h2 is bf16 -----------
__global__ __launch_bounds__(192)
void out_kernel(const u16* __restrict__ h2, const int* __restrict__ ids,
                const int* __restrict__ tms,
                const float* __restrict__ tw, const float* __restrict__ tb,
                float* __restrict__ out, int R, int Nn)
{
    int r = blockIdx.x;
    int c = threadIdx.x;
    if (r >= R) return;
    float v;
    if (c < HD) {
        int id = ids[r];
        v = (id >= 0 && id < Nn) ? bf2f(h2[(size_t)id * HD + c]) : 0.0f;
    } else {
        int j = c - HD;
        v = cosf((float)tms[r] * tw[j] + tb[j]);
    }
    out[(size_t)r * (HD + TD) + c] = v;
}

extern "C" void kernel_launch(void* const* d_in, const int* in_sizes, int n_in,
                              void* d_out, int out_size, void* d_ws, size_t ws_size,
                              hipStream_t stream)
{
    const float* h   = (const float*)d_in[0];
    const float* rel = (const float*)d_in[1];
    const float* wn1 = (const float*)d_in[2];
    const float* lw1 = (const float*)d_in[3];
    const float* ew1 = (const float*)d_in[4];
    const float* wn2 = (const float*)d_in[5];
    const float* lw2 = (const float*)d_in[6];
    const float* ew2 = (const float*)d_in[7];
    const float* tw  = (const float*)d_in[8];
    const float* tb  = (const float*)d_in[9];
    const int* src = (const int*)d_in[10];
    const int* dst = (const int*)d_in[11];
    const int* ety = (const int*)d_in[12];
    const int* ids = (const int*)d_in[13];
    const int* tms = (const int*)d_in[14];

    const int Nn  = in_sizes[0] / HD;
    const int E   = in_sizes[10];
    const int R   = in_sizes[13];
    const int NR2 = in_sizes[1] / HD;              // 460
    const int NBKT = (Nn + 127) >> BSH;            // 391
    const int M = NBKT * NBLK;                     // 100096 regions
    const int NBS = (M + 1023) / 1024;             // scan blocks (98)

    // ws: cnt | bsum | start | rowstart | elistA | elist | hbf | h1bf | Sn | h2bf | relbf | BT1 | BT2
    char* ws = (char*)d_ws;
    const size_t cntB  = ((size_t)M * 4 + 255) & ~(size_t)255;
    const size_t bsB   = ((size_t)NBS * 4 + 255) & ~(size_t)255;
    const size_t stB   = (((size_t)M + 1) * 4 + 255) & ~(size_t)255;
    const size_t rsB   = (((size_t)Nn + 1) * 4 + 255) & ~(size_t)255;
    int* cnt      = (int*)(ws);
    int* bsum     = (int*)(ws + cntB);
    int* start    = (int*)(ws + cntB + bsB);
    int* rowstart = (int*)(ws + cntB + bsB + stB);
    char* p       = ws + cntB + bsB + stB + rsB;
    u32* elistA = (u32*)p;   p += ((size_t)E * 4 + 255) & ~(size_t)255;
    u32* elist  = (u32*)p;   p += ((size_t)E * 4 + 255) & ~(size_t)255;
    u16* hbf    = (u16*)p;   p += (size_t)Nn * HD * 2;
    u16* h1bf   = (u16*)p;   p += (size_t)Nn * HD * 2;
    u16* Sn     = (u16*)p;   p += (size_t)Nn * HD * 2;
    u16* h2bf   = (u16*)p;   p += (size_t)Nn * HD * 2;
    u16* relbf  = (u16*)p;   p += ((size_t)NR2 * HD * 2 + 255) & ~(size_t)255;
    u16* BT1    = (u16*)p;   p += HD * 256 * 2;
    u16* BT2    = (u16*)p;

    const int n4 = Nn * HD / 4;
    const int r4 = NR2 * HD / 4;
    const int gb = (Nn + 127) / 128;

    // conversions (independent of CSR build)
    conv_kernel<<<(n4 + 255) / 256, 256, 0, stream>>>((const float4*)h, (ushort4*)hbf, n4);
    conv_kernel<<<(r4 + 255) / 256, 256, 0, stream>>>((const float4*)rel, (ushort4*)relbf, r4);
    bt_kernel<<<128, 256, 0, stream>>>(wn1, lw1, BT1);
    bt_kernel<<<128, 256, 0, stream>>>(wn2, lw2, BT2);

    // CSR build — contention-free regions (all buffers fully overwritten each call)
    cntA<<<NBLK, 256, 0, stream>>>(dst, E, cnt, NBKT);
    scan1_kernel<<<NBS, 256, 0, stream>>>(cnt, bsum, M);
    scan2_kernel<<<1, 64, 0, stream>>>(bsum, NBS, &start[M]);
    scan3_kernel<<<NBS, 1024, 0, stream>>>(cnt, bsum, start, M);
    passA2<<<NBLK, 256, 0, stream>>>(src, dst, ety, start, elistA, E, NBKT);
    passB<<<NBKT, 256, 0, stream>>>(elistA, start, elist, rowstart, Nn, E, NBKT);

    // layer 1: h(bf16) -> h1(bf16)
    gagg_kernel<<<Nn, 64, 0, stream>>>((const u32*)hbf, (const u32*)relbf,
                                       elist, rowstart, (u32*)Sn, Nn);
    mfma_kernel<<<gb, 256, 0, stream>>>(Sn, hbf, BT1, rowstart, ew1, h1bf, Nn);

    // layer 2: h1(bf16) -> h2(bf16)
    gagg_kernel<<<Nn, 64, 0, stream>>>((const u32*)h1bf, (const u32*)relbf,
                                       elist, rowstart, (u32*)Sn, Nn);
    mfma_kernel<<<gb, 256, 0, stream>>>(Sn, h1bf, BT2, rowstart, ew2, h2bf, Nn);

    // output (fp32), gathering bf16 h2
    out_kernel<<<R, 192, 0, stream>>>(h2bf, ids, tms, tw, tb, (float*)d_out, R, Nn);
}

// Round 27
// 147.942 us; speedup vs baseline: 1.0362x; 1.0362x over previous
//
#include <hip/hip_runtime.h>

// Round 27 (final): exact r25 pipeline — best measured (148.4 us).
// bf16 MFMA layers (BT in swizzled LDS), 1-wave-per-node ILP-8 gather,
// contention-free bucketed CSR build, bf16 intermediates.

#define HD 128
#define TD 64
#define BSH 7                 // 128 nodes per bucket
#define NBLK 256              // passA blocks (= regions per bucket)
constexpr float SLOPE = 11.0f / 48.0f;

typedef unsigned short u16;
typedef unsigned int u32;
typedef short bf16x8 __attribute__((ext_vector_type(8)));
typedef float f32x4 __attribute__((ext_vector_type(4)));

__device__ __forceinline__ float bf2f(u16 b) {
    return __uint_as_float(((u32)b) << 16);
}
__device__ __forceinline__ u16 f2bf(float f) {
    u32 u = __float_as_uint(f);
    u += 0x7FFFu + ((u >> 16) & 1u);  // RNE
    return (u16)(u >> 16);
}

// ---- fp32 -> bf16 convert -------------------------------------------------
__global__ __launch_bounds__(256)
void conv_kernel(const float4* __restrict__ in, ushort4* __restrict__ out, int n4)
{
    int i = blockIdx.x * 256 + threadIdx.x;
    if (i >= n4) return;
    float4 v = in[i];
    ushort4 o;
    o.x = f2bf(v.x); o.y = f2bf(v.y); o.z = f2bf(v.z); o.w = f2bf(v.w);
    out[i] = o;
}

// ---- build BT[col][k] bf16, k<128 from Wn, k>=128 from Lw ------------------
__global__ __launch_bounds__(256)
void bt_kernel(const float* __restrict__ Wn, const float* __restrict__ Lw,
               u16* __restrict__ BT)
{
    int idx = blockIdx.x * 256 + threadIdx.x;   // 128*256 = 32768
    int c = idx >> 8, k = idx & 255;
    float v = (k < HD) ? Wn[k * HD + c] : Lw[(k - HD) * HD + c];
    BT[(size_t)c * 256 + k] = f2bf(v);
}

// ---- cntA: per-block bucket histogram -> cnt[bucket*NBLK + blk] ------------
__global__ __launch_bounds__(256)
void cntA(const int* __restrict__ dst, int E, int* __restrict__ cnt, int NBKT)
{
    __shared__ int hist[512];
    const int b = blockIdx.x, t = threadIdx.x;
    for (int i = t; i < NBKT; i += 256) hist[i] = 0;
    __syncthreads();
    const int chunk = (E + NBLK - 1) / NBLK;
    const int e0 = b * chunk;
    const int e1 = (e0 + chunk < E) ? e0 + chunk : E;
    for (int e = e0 + t; e < e1; e += 256)
        atomicAdd(&hist[dst[e] >> BSH], 1);
    __syncthreads();
    for (int i = t; i < NBKT; i += 256)
        cnt[(size_t)i * NBLK + b] = hist[i];
}

// ---- hierarchical exclusive scan over M = NBKT*NBLK values -----------------
__global__ __launch_bounds__(256)
void scan1_kernel(const int* __restrict__ v, int* __restrict__ bsum, int M)
{
    __shared__ int red[256];
    const int b = blockIdx.x, t = threadIdx.x;
    int s = 0;
    #pragma unroll
    for (int j = 0; j < 4; j++) {
        int i = b * 1024 + j * 256 + t;
        if (i < M) s += v[i];
    }
    red[t] = s;
    __syncthreads();
    for (int off = 128; off; off >>= 1) {
        if (t < off) red[t] += red[t + off];
        __syncthreads();
    }
    if (t == 0) bsum[b] = red[0];
}

__global__ __launch_bounds__(64)
void scan2_kernel(int* __restrict__ bsum, int NB, int* __restrict__ totalOut)
{
    if (threadIdx.x == 0 && blockIdx.x == 0) {
        int acc = 0;
        for (int b = 0; b < NB; b++) { int x = bsum[b]; bsum[b] = acc; acc += x; }
        *totalOut = acc;   // == E
    }
}

__global__ __launch_bounds__(1024)
void scan3_kernel(const int* __restrict__ v, const int* __restrict__ bsum,
                  int* __restrict__ start, int M)
{
    __shared__ int buf[1024];
    const int b = blockIdx.x, t = threadIdx.x;
    const int i = b * 1024 + t;
    const int x = (i < M) ? v[i] : 0;
    buf[t] = x;
    __syncthreads();
    for (int off = 1; off < 1024; off <<= 1) {
        int y = (t >= off) ? buf[t - off] : 0;
        __syncthreads();
        buf[t] += y;
        __syncthreads();
    }
    if (i < M) start[i] = bsum[b] + buf[t] - x;   // exclusive
}

// ---- passA2: append via per-block LDS cursors (no global atomics) ----------
// entry = (dloc<<25) | (ety<<16) | src
__global__ __launch_bounds__(256)
void passA2(const int* __restrict__ src, const int* __restrict__ dst,
            const int* __restrict__ ety, const int* __restrict__ start,
            u32* __restrict__ elistA, int E, int NBKT)
{
    __shared__ int cur[512];
    const int b = blockIdx.x, t = threadIdx.x;
    for (int i = t; i < NBKT; i += 256) cur[i] = start[(size_t)i * NBLK + b];
    __syncthreads();
    const int chunk = (E + NBLK - 1) / NBLK;
    const int e0 = b * chunk;
    const int e1 = (e0 + chunk < E) ? e0 + chunk : E;
    for (int e = e0 + t; e < e1; e += 256) {
        int d = dst[e];
        u32 entry = ((u32)(d & 127) << 25) | ((u32)ety[e] << 16) | (u32)src[e];
        int pos = atomicAdd(&cur[d >> BSH], 1);
        elistA[pos] = entry;
    }
}

// ---- passB: per-bucket sort into per-node CSR + rowstart -------------------
__global__ __launch_bounds__(256)
void passB(const u32* __restrict__ elistA, const int* __restrict__ start,
           u32* __restrict__ elist, int* __restrict__ rowstart, int Nn, int E,
           int NBKT)
{
    __shared__ int cnt[128];
    __shared__ int ofs[128];
    const int b = blockIdx.x, t = threadIdx.x;
    const int beg = start[(size_t)b * NBLK];
    const int end = (b + 1 < NBKT) ? start[(size_t)(b + 1) * NBLK] : E;
    if (t < 128) cnt[t] = 0;
    __syncthreads();
    for (int i = beg + t; i < end; i += 256)
        atomicAdd(&cnt[elistA[i] >> 25], 1);
    __syncthreads();
    if (t == 0) {
        int acc = 0;
        for (int j = 0; j < 128; j++) { ofs[j] = acc; acc += cnt[j]; }
    }
    __syncthreads();
    const int n0 = b << BSH;
    if (t < 128 && n0 + t < Nn) rowstart[n0 + t] = beg + ofs[t];
    if (b == 0 && t == 0) rowstart[Nn] = E;
    __syncthreads();
    for (int i = beg + t; i < end; i += 256) {
        u32 v = elistA[i];
        int p = atomicAdd(&ofs[v >> 25], 1);
        elist[beg + p] = v & 0x01ffffffu;   // (ety<<16)|src
    }
}

// ---- gather-aggregate (bf16 h + bf16 rel), pre-scaled by 1/max(deg,1) ------
// block = one dst node, 64 threads; thread c owns cols 2c, 2c+1 (u32 = 2 bf16)
// Tail edges handled as a MASKED ILP-8 batch (no serial latency chain).
__global__ __launch_bounds__(64)
void gagg_kernel(const u32* __restrict__ hbf2, const u32* __restrict__ relbf2,
                 const u32* __restrict__ elist, const int* __restrict__ rowstart,
                 u32* __restrict__ Sn2, int Nn)
{
    int n = blockIdx.x;
    if (n >= Nn) return;
    int c = threadIdx.x;
    int beg = rowstart[n], end = rowstart[n + 1];
    float ae[8] = {}, ao[8] = {};
    int i = beg;
    for (; i + 8 <= end; i += 8) {
        #pragma unroll
        for (int j = 0; j < 8; j++) {
            u32 v = elist[i + j];
            u32 hv = hbf2[(size_t)(v & 0xffffu) * 64 + c];
            u32 rv = relbf2[(size_t)(v >> 16) * 64 + c];
            ae[j] += bf2f((u16)(hv & 0xffffu)) - bf2f((u16)(rv & 0xffffu));
            ao[j] += bf2f((u16)(hv >> 16)) - bf2f((u16)(rv >> 16));
        }
    }
    if (i < end) {
        // masked ILP-8 tail: clamp index, zero masked contributions
        #pragma unroll
        for (int j = 0; j < 8; j++) {
            int idx = i + j;
            bool ok = idx < end;
            u32 v = elist[ok ? idx : end - 1];
            u32 hv = hbf2[(size_t)(v & 0xffffu) * 64 + c];
            u32 rv = relbf2[(size_t)(v >> 16) * 64 + c];
            float de = bf2f((u16)(hv & 0xffffu)) - bf2f((u16)(rv & 0xffffu));
            float doo = bf2f((u16)(hv >> 16)) - bf2f((u16)(rv >> 16));
            ae[j] += ok ? de : 0.0f;
            ao[j] += ok ? doo : 0.0f;
        }
    }
    float se = ((ae[0] + ae[1]) + (ae[2] + ae[3])) + ((ae[4] + ae[5]) + (ae[6] + ae[7]));
    float so = ((ao[0] + ao[1]) + (ao[2] + ao[3])) + ((ao[4] + ao[5]) + (ao[6] + ao[7]));
    int d = end - beg;
    float nrm = 1.0f / (float)((d > 0) ? d : 1);
    se *= nrm; so *= nrm;
    Sn2[(size_t)n * 64 + c] = (u32)f2bf(se) | ((u32)f2bf(so) << 16);
}

// ---- MFMA GEMM: out = rrelu([Sn | Hn](bf16, K=256) @ BT^T), BT in LDS ------
__global__ __launch_bounds__(256)
void mfma_kernel(const u16* __restrict__ Sn, const u16* __restrict__ Hn,
                 const u16* __restrict__ BT, const int* __restrict__ rowstart,
                 const float* __restrict__ Ew, u16* __restrict__ Out, int Nn)
{
    __shared__ u16 BTs[128 * 256];   // 64 KB, swizzled

    const int tid = threadIdx.x;
    #pragma unroll
    for (int j = 0; j < 16; j++) {
        int chunk = tid + j * 256;
        int byte = chunk << 4;
        int row = byte >> 9;
        int sw = byte ^ ((row & 7) << 4);
        *(ulonglong2*)((char*)BTs + sw) = *(const ulonglong2*)((const char*)BT + byte);
    }
    __syncthreads();

    const int lane = tid & 63;
    const int wave = tid >> 6;
    const int row0 = blockIdx.x * 128 + wave * 32;
    const int lr = lane & 15;
    const int lk = (lane >> 4) * 8;

    f32x4 acc[2][8];
    #pragma unroll
    for (int m = 0; m < 2; m++)
        #pragma unroll
        for (int n = 0; n < 8; n++)
            acc[m][n] = (f32x4){0.f, 0.f, 0.f, 0.f};

    int r0 = row0 + lr;      if (r0 >= Nn) r0 = Nn - 1;
    int r1 = row0 + 16 + lr; if (r1 >= Nn) r1 = Nn - 1;
    const size_t rb0 = (size_t)r0 * HD, rb1 = (size_t)r1 * HD;

    #pragma unroll
    for (int ks = 0; ks < 8; ks++) {
        const u16* A = (ks < 4) ? Sn : Hn;
        const int kc = (ks & 3) * 32 + lk;
        bf16x8 a0 = *(const bf16x8*)&A[rb0 + kc];
        bf16x8 a1 = *(const bf16x8*)&A[rb1 + kc];
        #pragma unroll
        for (int nf = 0; nf < 8; nf++) {
            const int brow = nf * 16 + lr;
            int boff = (brow << 9) + ((ks * 32 + lk) << 1);
            boff ^= (brow & 7) << 4;
            bf16x8 b = *(const bf16x8*)((const char*)BTs + boff);
            acc[0][nf] = __builtin_amdgcn_mfma_f32_16x16x32_bf16(a0, b, acc[0][nf], 0, 0, 0);
            acc[1][nf] = __builtin_amdgcn_mfma_f32_16x16x32_bf16(a1, b, acc[1][nf], 0, 0, 0);
        }
    }

    #pragma unroll
    for (int mf = 0; mf < 2; mf++) {
        #pragma unroll
        for (int r = 0; r < 4; r++) {
            const int row = row0 + mf * 16 + (lane >> 4) * 4 + r;
            if (row >= Nn) continue;
            const int d = rowstart[row + 1] - rowstart[row];
            #pragma unroll
            for (int nf = 0; nf < 8; nf++) {
                const int col = nf * 16 + lr;
                float o = acc[mf][nf][r];
                if (d == 0) {
                    // isolated node (rare): Sn row is 0; loop term must use Ew
                    o = 0.f;
                    for (int k = 0; k < HD; k++)
                        o = fmaf(bf2f(Hn[(size_t)row * HD + k]), Ew[(size_t)k * HD + col], o);
                }
                o = (o >= 0.f) ? o : o * SLOPE;
                Out[(size_t)row * HD + col] = f2bf(o);
            }
        }
    }
}

// ---- gather + time embedding -> FP32 output [R, 192]; h2 is bf16 -----------
__global__ __launch_bounds__(192)
void out_kernel(const u16* __restrict__ h2, const int* __restrict__ ids,
                const int* __restrict__ tms,
                const float* __restrict__ tw, const float* __restrict__ tb,
                float* __restrict__ out, int R, int Nn)
{
    int r = blockIdx.x;
    int c = threadIdx.x;
    if (r >= R) return;
    float v;
    if (c < HD) {
        int id = ids[r];
        v = (id >= 0 && id < Nn) ? bf2f(h2[(size_t)id * HD + c]) : 0.0f;
    } else {
        int j = c - HD;
        v = cosf((float)tms[r] * tw[j] + tb[j]);
    }
    out[(size_t)r * (HD + TD) + c] = v;
}

extern "C" void kernel_launch(void* const* d_in, const int* in_sizes, int n_in,
                              void* d_out, int out_size, void* d_ws, size_t ws_size,
                              hipStream_t stream)
{
    const float* h   = (const float*)d_in[0];
    const float* rel = (const float*)d_in[1];
    const float* wn1 = (const float*)d_in[2];
    const float* lw1 = (const float*)d_in[3];
    const float* ew1 = (const float*)d_in[4];
    const float* wn2 = (const float*)d_in[5];
    const float* lw2 = (const float*)d_in[6];
    const float* ew2 = (const float*)d_in[7];
    const float* tw  = (const float*)d_in[8];
    const float* tb  = (const float*)d_in[9];
    const int* src = (const int*)d_in[10];
    const int* dst = (const int*)d_in[11];
    const int* ety = (const int*)d_in[12];
    const int* ids = (const int*)d_in[13];
    const int* tms = (const int*)d_in[14];

    const int Nn  = in_sizes[0] / HD;
    const int E   = in_sizes[10];
    const int R   = in_sizes[13];
    const int NR2 = in_sizes[1] / HD;              // 460
    const int NBKT = (Nn + 127) >> BSH;            // 391
    const int M = NBKT * NBLK;                     // 100096 regions
    const int NBS = (M + 1023) / 1024;             // scan blocks (98)

    // ws: cnt | bsum | start | rowstart | elistA | elist | hbf | h1bf | Sn | h2bf | relbf | BT1 | BT2
    char* ws = (char*)d_ws;
    const size_t cntB  = ((size_t)M * 4 + 255) & ~(size_t)255;
    const size_t bsB   = ((size_t)NBS * 4 + 255) & ~(size_t)255;
    const size_t stB   = (((size_t)M + 1) * 4 + 255) & ~(size_t)255;
    const size_t rsB   = (((size_t)Nn + 1) * 4 + 255) & ~(size_t)255;
    int* cnt      = (int*)(ws);
    int* bsum     = (int*)(ws + cntB);
    int* start    = (int*)(ws + cntB + bsB);
    int* rowstart = (int*)(ws + cntB + bsB + stB);
    char* p       = ws + cntB + bsB + stB + rsB;
    u32* elistA = (u32*)p;   p += ((size_t)E * 4 + 255) & ~(size_t)255;
    u32* elist  = (u32*)p;   p += ((size_t)E * 4 + 255) & ~(size_t)255;
    u16* hbf    = (u16*)p;   p += (size_t)Nn * HD * 2;
    u16* h1bf   = (u16*)p;   p += (size_t)Nn * HD * 2;
    u16* Sn     = (u16*)p;   p += (size_t)Nn * HD * 2;
    u16* h2bf   = (u16*)p;   p += (size_t)Nn * HD * 2;
    u16* relbf  = (u16*)p;   p += ((size_t)NR2 * HD * 2 + 255) & ~(size_t)255;
    u16* BT1    = (u16*)p;   p += HD * 256 * 2;
    u16* BT2    = (u16*)p;

    const int n4 = Nn * HD / 4;
    const int r4 = NR2 * HD / 4;
    const int gb = (Nn + 127) / 128;

    // conversions (independent of CSR build)
    conv_kernel<<<(n4 + 255) / 256, 256, 0, stream>>>((const float4*)h, (ushort4*)hbf, n4);
    conv_kernel<<<(r4 + 255) / 256, 256, 0, stream>>>((const float4*)rel, (ushort4*)relbf, r4);
    bt_kernel<<<128, 256, 0, stream>>>(wn1, lw1, BT1);
    bt_kernel<<<128, 256, 0, stream>>>(wn2, lw2, BT2);

    // CSR build — contention-free regions (all buffers fully overwritten each call)
    cntA<<<NBLK, 256, 0, stream>>>(dst, E, cnt, NBKT);
    scan1_kernel<<<NBS, 256, 0, stream>>>(cnt, bsum, M);
    scan2_kernel<<<1, 64, 0, stream>>>(bsum, NBS, &start[M]);
    scan3_kernel<<<NBS, 1024, 0, stream>>>(cnt, bsum, start, M);
    passA2<<<NBLK, 256, 0, stream>>>(src, dst, ety, start, elistA, E, NBKT);
    passB<<<NBKT, 256, 0, stream>>>(elistA, start, elist, rowstart, Nn, E, NBKT);

    // layer 1: h(bf16) -> h1(bf16)
    gagg_kernel<<<Nn, 64, 0, stream>>>((const u32*)hbf, (const u32*)relbf,
                                       elist, rowstart, (u32*)Sn, Nn);
    mfma_kernel<<<gb, 256, 0, stream>>>(Sn, hbf, BT1, rowstart, ew1, h1bf, Nn);

    // layer 2: h1(bf16) -> h2(bf16)
    gagg_kernel<<<Nn, 64, 0, stream>>>((const u32*)h1bf, (const u32*)relbf,
                                       elist, rowstart, (u32*)Sn, Nn);
    mfma_kernel<<<gb, 256, 0, stream>>>(Sn, h1bf, BT2, rowstart, ew2, h2bf, Nn);

    // output (fp32), gathering bf16 h2
    out_kernel<<<R, 192, 0, stream>>>(h2bf, ids, tms, tw, tb, (float*)d_out, R, Nn);
}